// Round 3
// baseline (219.398 us; speedup 1.0000x reference)
//
#include <hip/hip_runtime.h>

#define EPS 1e-8f

using short8 = __attribute__((ext_vector_type(8))) short;
using f32x4  = __attribute__((ext_vector_type(4))) float;
typedef unsigned short u16;

#define WAITV(N) asm volatile("s_waitcnt vmcnt(" #N ")" ::: "memory")
#define WAITLGKM0() do { asm volatile("s_waitcnt lgkmcnt(0)" ::: "memory"); \
                         __builtin_amdgcn_sched_barrier(0); } while (0)
#define BARRIER() do { __builtin_amdgcn_s_barrier(); \
                       asm volatile("" ::: "memory"); } while (0)

__device__ __forceinline__ u16 f2bf(float f) {
    union { float f; unsigned u; } v; v.f = f;
    unsigned u = v.u;
    return (u16)((u + 0x7FFFu + ((u >> 16) & 1u)) >> 16);
}

__device__ __forceinline__ void g2l16(const void* gsrc, void* ldst) {
    __builtin_amdgcn_global_load_lds(
        (const __attribute__((address_space(1))) unsigned int*)gsrc,
        (__attribute__((address_space(3))) unsigned int*)ldst, 16, 0, 0);
}

// ---------------- kernel 1: style[b][i] = dot(w[b], affine_w[i]) + affine_b[i] + 1
__global__ void style_kernel(const float* __restrict__ w,        // [8][512]
                             const float* __restrict__ affine_w, // [256][512]
                             const float* __restrict__ affine_b, // [256]
                             float* __restrict__ style) {        // [8][256]
    int b = blockIdx.x;
    int i = threadIdx.x;
    __shared__ float wb[512];
    for (int z = threadIdx.x; z < 512; z += 256) wb[z] = w[b * 512 + z];
    __syncthreads();
    const float* aw = affine_w + i * 512;
    float acc = 0.f;
#pragma unroll 4
    for (int z = 0; z < 512; z += 4) {
        float4 a4 = *reinterpret_cast<const float4*>(aw + z);
        acc += a4.x * wb[z] + a4.y * wb[z + 1] + a4.z * wb[z + 2] + a4.w * wb[z + 3];
    }
    style[b * 256 + i] = acc + affine_b[i] + 1.0f;
}

// ---------------- kernel 2: modulate + demodulate, pack bf16 weights
// wgt layout: bf16 [b][t(9)][g(32)][o(256)][j(8)], ic = g*8 + j
__global__ void modw_kernel(const float* __restrict__ weight, // [256][256][3][3]
                            const float* __restrict__ style,  // [8][256]
                            u16* __restrict__ wgt) {
    int b = blockIdx.x >> 8;
    int o = blockIdx.x & 255;
    int ic = threadIdx.x; // 256 threads
    float s = style[b * 256 + ic];
    const float* wp = weight + (size_t)(o * 256 + ic) * 9;
    float m[9];
    float ss = 0.f;
#pragma unroll
    for (int t = 0; t < 9; ++t) { m[t] = wp[t] * s; ss += m[t] * m[t]; }
#pragma unroll
    for (int off = 32; off > 0; off >>= 1) ss += __shfl_down(ss, off);
    __shared__ float part[4];
    int lane = threadIdx.x & 63, wid = threadIdx.x >> 6;
    if (lane == 0) part[wid] = ss;
    __syncthreads();
    float denom = rsqrtf(part[0] + part[1] + part[2] + part[3] + EPS);
    int g = ic >> 3, j = ic & 7;
#pragma unroll
    for (int t = 0; t < 9; ++t) {
        size_t idx = ((((size_t)(b * 9 + t) * 32 + g) * 256 + o) << 3) + j;
        wgt[idx] = f2bf(m[t] * denom);
    }
}

// ---------------- kernel 3: x fp32 [8][256][128][128] -> bf16 xb [8][32][128][128][8]
__global__ __launch_bounds__(256) void xform_kernel(const float* __restrict__ x,
                                                    u16* __restrict__ xb) {
    int s = blockIdx.x * 256 + threadIdx.x; // (b,g,h,w)
    int w = s & 127, h = (s >> 7) & 127, g = (s >> 14) & 31, b = s >> 19;
    const float* xp = x + (((size_t)(b * 256 + g * 8) * 128 + h) * 128 + w);
    union { u16 u[8]; short8 v; } pk;
#pragma unroll
    for (int j = 0; j < 8; ++j) pk.u[j] = f2bf(xp[(size_t)j * 16384]);
    *reinterpret_cast<short8*>(&xb[(size_t)s * 8]) = pk.v;
}

// ---------------- kernel 4: implicit-GEMM conv, counted-vmcnt pipeline
// block = (b, ht): 256 o x (2 rows x 128 w), 512 threads (8 waves).
// 72 phases = 8 ic-chunks x 9 taps. A: 3-deep ring, prefetch dist 2.
// X: LDS double-buffer, prefetched 9 phases early. No vmcnt(0) in main loop.
__global__ __launch_bounds__(512, 2) void conv_kernel(
    const u16* __restrict__ xb,  // [8][32][128][128][8] bf16
    const u16* __restrict__ wgt, // [8][9][32][256][8] bf16
    float* __restrict__ out) {   // [8][256][128][128]

    __shared__ __align__(16) u16 Xs[2][4][4][130][8]; // 66560 B [buf][row][g][w130][j8]
    __shared__ __align__(16) u16 As[3][4][256][8];    // 49152 B [ring][g][o256][j8]
    __shared__ __align__(16) u16 trash[512];          // 1024 B OOB-redirect sink

    int bid = blockIdx.x;
    int swz = (bid & 7) * 64 + (bid >> 3); // grid 512 = 8*64, bijective
    int ht = swz & 63, b = swz >> 6;
    int h0 = ht * 2;

    int tid = threadIdx.x, lane = tid & 63, wid = tid >> 6;
    int wm = wid >> 1, wr = wid & 1; // wave -> (o quarter 64, row)
    int l15 = lane & 15, lg = lane >> 4;

    auto stageA = [&](int p, int ring) { // 2 loads/wave, uniform
        int t = p % 9, c = p / 9;
        const u16* wbase = wgt + ((size_t)(b * 9 + t) * 32 + c * 4) * (256 * 8);
#pragma unroll
        for (int k = 0; k < 2; ++k) {
            int seg = wid * 2 + k, g = seg >> 2, oq = seg & 3;
            const u16* src = wbase + ((size_t)g * 256 + oq * 64 + lane) * 8;
            g2l16(src, &As[ring][g][oq * 64][0]);
        }
    };
    auto stageX = [&](int c1, int bx) { // 4 loads/wave, uniform (OOB -> trash)
        int row = wid >> 1;
        int hr = h0 + row - 1;
        bool oob = ((unsigned)hr >= 128u);
        int hc = oob ? 0 : hr;
#pragma unroll
        for (int k = 0; k < 4; ++k) {
            int g = (wid * 2 + (k >> 1)) & 3, half = k & 1;
            const u16* src = xb +
                ((((size_t)(b * 32 + c1 * 4 + g)) * 128 + hc) * 128 + half * 64 + lane) * 8;
            void* dst = oob ? (void*)trash : (void*)&Xs[bx][row][g][1 + half * 64][0];
            g2l16(src, dst);
        }
    };

    // zero both X buffers (borders + OOB rows stay zero forever)
    {
        short8 z = {0, 0, 0, 0, 0, 0, 0, 0};
        short8* p0 = reinterpret_cast<short8*>(&Xs[0][0][0][0][0]);
        for (int i = tid; i < 4160; i += 512) p0[i] = z;
    }
    __syncthreads();

    stageX(0, 0);   // X chunk 0 -> buf 0
    stageA(0, 0);
    stageA(1, 1);
    WAITV(2);       // X0 + A0 landed; A1 in flight
    BARRIER();

    f32x4 acc[4][8] = {};

    for (int c = 0; c < 8; ++c) {
        for (int t = 0; t < 9; ++t) {
            int p = c * 9 + t;
            if (t == 0 && c < 7) stageX(c + 1, (c + 1) & 1);
            if (p <= 69) stageA(p + 2, (p + 2) % 3);

            int ring = p % 3;
            int kh = t / 3, kw = t - kh * 3;
            short8 af[4], bx8[8];
#pragma unroll
            for (int mi = 0; mi < 4; ++mi)
                af[mi] = *reinterpret_cast<const short8*>(
                    &As[ring][lg][wm * 64 + mi * 16 + l15][0]);
#pragma unroll
            for (int ni = 0; ni < 8; ++ni)
                bx8[ni] = *reinterpret_cast<const short8*>(
                    &Xs[c & 1][wr + kh][lg][ni * 16 + l15 + kw][0]);
            WAITLGKM0();
            __builtin_amdgcn_s_setprio(1);
#pragma unroll
            for (int mi = 0; mi < 4; ++mi)
#pragma unroll
                for (int ni = 0; ni < 8; ++ni)
                    acc[mi][ni] = __builtin_amdgcn_mfma_f32_16x16x32_bf16(
                        af[mi], bx8[ni], acc[mi][ni], 0, 0, 0);
            __builtin_amdgcn_s_setprio(0);
            __builtin_amdgcn_sched_barrier(0);

            if (t == 0 && c < 7)  { WAITV(6); } // leave X(c+1):4 + A(p+2):2
            else if (p <= 69)     { WAITV(2); } // leave A(p+2):2
            else if (p == 70)     { WAITV(0); } // drain A(71)
            BARRIER();
        }
    }

    // epilogue: C/D layout col=lane&15 (w), row=(lane>>4)*4+r (o)
    int h = h0 + wr;
#pragma unroll
    for (int mi = 0; mi < 4; ++mi) {
        int o = wm * 64 + mi * 16 + lg * 4;
#pragma unroll
        for (int ni = 0; ni < 8; ++ni) {
            int w_ = ni * 16 + l15;
            float* op = out + (((size_t)(b * 256 + o) * 128 + h) * 128 + w_);
#pragma unroll
            for (int r = 0; r < 4; ++r)
                op[(size_t)r * 16384] = acc[mi][ni][r];
        }
    }
}

extern "C" void kernel_launch(void* const* d_in, const int* in_sizes, int n_in,
                              void* d_out, int out_size, void* d_ws, size_t ws_size,
                              hipStream_t stream) {
    const float* x        = (const float*)d_in[0];
    const float* w        = (const float*)d_in[1];
    const float* weight   = (const float*)d_in[2];
    const float* affine_w = (const float*)d_in[3];
    const float* affine_b = (const float*)d_in[4];
    float* out = (float*)d_out;

    float* style = (float*)d_ws;                                   // 8 KB
    u16* wgt = (u16*)((char*)d_ws + 8192);                         // 9.44 MB
    u16* xbuf = (u16*)((char*)d_ws + 8192 + 9437184);              // 64 MB

    xform_kernel<<<16384, 256, 0, stream>>>(x, xbuf);
    style_kernel<<<8, 256, 0, stream>>>(w, affine_w, affine_b, style);
    modw_kernel<<<2048, 256, 0, stream>>>(weight, style, wgt);
    conv_kernel<<<512, 512, 0, stream>>>(xbuf, wgt, out);
}

// Round 4
// 199.010 us; speedup vs baseline: 1.1024x; 1.1024x over previous
//
#include <hip/hip_runtime.h>

#define EPS 1e-8f

using short8 = __attribute__((ext_vector_type(8))) short;
using f32x4  = __attribute__((ext_vector_type(4))) float;
typedef unsigned short u16;

#define WAITV(N) asm volatile("s_waitcnt vmcnt(" #N ")" ::: "memory")
#define BARRIER() do { __builtin_amdgcn_s_barrier(); \
                       asm volatile("" ::: "memory"); } while (0)

__device__ __forceinline__ u16 f2bf(float f) {
    union { float f; unsigned u; } v; v.f = f;
    unsigned u = v.u;
    return (u16)((u + 0x7FFFu + ((u >> 16) & 1u)) >> 16);
}

__device__ __forceinline__ void g2l16(const void* gsrc, void* ldst) {
    __builtin_amdgcn_global_load_lds(
        (const __attribute__((address_space(1))) unsigned int*)gsrc,
        (__attribute__((address_space(3))) unsigned int*)ldst, 16, 0, 0);
}

// ---------------- kernel 1: style[b][i] = dot(w[b], affine_w[i]) + affine_b[i] + 1
__global__ void style_kernel(const float* __restrict__ w,        // [8][512]
                             const float* __restrict__ affine_w, // [256][512]
                             const float* __restrict__ affine_b, // [256]
                             float* __restrict__ style) {        // [8][256]
    int b = blockIdx.x;
    int i = threadIdx.x;
    __shared__ float wb[512];
    for (int z = threadIdx.x; z < 512; z += 256) wb[z] = w[b * 512 + z];
    __syncthreads();
    const float* aw = affine_w + i * 512;
    float acc = 0.f;
#pragma unroll 4
    for (int z = 0; z < 512; z += 4) {
        float4 a4 = *reinterpret_cast<const float4*>(aw + z);
        acc += a4.x * wb[z] + a4.y * wb[z + 1] + a4.z * wb[z + 2] + a4.w * wb[z + 3];
    }
    style[b * 256 + i] = acc + affine_b[i] + 1.0f;
}

// ---------------- kernel 2: modulate + demodulate, pack bf16 weights
// wgt layout: bf16 [b][t(9)][g(32)][o(256)][j(8)], ic = g*8 + j
__global__ void modw_kernel(const float* __restrict__ weight, // [256][256][3][3]
                            const float* __restrict__ style,  // [8][256]
                            u16* __restrict__ wgt) {
    int b = blockIdx.x >> 8;
    int o = blockIdx.x & 255;
    int ic = threadIdx.x; // 256 threads
    float s = style[b * 256 + ic];
    const float* wp = weight + (size_t)(o * 256 + ic) * 9;
    float m[9];
    float ss = 0.f;
#pragma unroll
    for (int t = 0; t < 9; ++t) { m[t] = wp[t] * s; ss += m[t] * m[t]; }
#pragma unroll
    for (int off = 32; off > 0; off >>= 1) ss += __shfl_down(ss, off);
    __shared__ float part[4];
    int lane = threadIdx.x & 63, wid = threadIdx.x >> 6;
    if (lane == 0) part[wid] = ss;
    __syncthreads();
    float denom = rsqrtf(part[0] + part[1] + part[2] + part[3] + EPS);
    int g = ic >> 3, j = ic & 7;
#pragma unroll
    for (int t = 0; t < 9; ++t) {
        size_t idx = ((((size_t)(b * 9 + t) * 32 + g) * 256 + o) << 3) + j;
        wgt[idx] = f2bf(m[t] * denom);
    }
}

// ---------------- kernel 3: x fp32 [8][256][128][128] -> bf16 xb [8][32][128][128][8]
__global__ __launch_bounds__(256) void xform_kernel(const float* __restrict__ x,
                                                    u16* __restrict__ xb) {
    int s = blockIdx.x * 256 + threadIdx.x; // (b,g,h,w)
    int w = s & 127, h = (s >> 7) & 127, g = (s >> 14) & 31, b = s >> 19;
    const float* xp = x + (((size_t)(b * 256 + g * 8) * 128 + h) * 128 + w);
    union { u16 u[8]; short8 v; } pk;
#pragma unroll
    for (int j = 0; j < 8; ++j) pk.u[j] = f2bf(xp[(size_t)j * 16384]);
    *reinterpret_cast<short8*>(&xb[(size_t)s * 8]) = pk.v;
}

// ---------------- kernel 4: implicit-GEMM conv, FIFO-consistent counted-vmcnt
// block = (b, ot, ht): 128 o x (2 rows x 128 w), 256 threads (4 waves), 2 blocks/CU.
// A: 5-deep LDS ring, prefetch dist 4. X: single LDS buf; next chunk reg-staged
// at t==5, ds_written at t==8 boundary. vmcnt never 0 in main loop.
__global__ __launch_bounds__(256, 2) void conv_kernel(
    const u16* __restrict__ xb,  // [8][32][128][128][8] bf16
    const u16* __restrict__ wgt, // [8][9][32][256][8] bf16
    float* __restrict__ out) {   // [8][256][128][128]

    __shared__ __align__(16) u16 Xs[4][4][130][8]; // 33280 B [row][g][w130][j8]
    __shared__ __align__(16) u16 As[5][4][128][8]; // 40960 B [ring][g][o128][j8]
    __shared__ __align__(16) u16 trash[1024];      // chunk-0 OOB sink

    int bid = blockIdx.x;
    int swz = (bid & 7) * 128 + (bid >> 3); // grid 1024 = 8*128, bijective
    int ht = swz & 63, ot = (swz >> 6) & 1, b = swz >> 7;
    int h0 = ht * 2;

    int tid = threadIdx.x, lane = tid & 63, wid = tid >> 6;
    int wm = wid >> 1, wr = wid & 1; // wave -> (o half 64, row)
    int l15 = lane & 15, lg = lane >> 4;

    auto stageA = [&](int cc, int tt, int ring) { // 2 loads/wave, uniform
        const u16* wbase = wgt + ((size_t)(b * 9 + tt) * 32) * 2048;
#pragma unroll
        for (int k = 0; k < 2; ++k) {
            int seg = wid * 2 + k, g = seg >> 1, oh = seg & 1;
            const u16* src = wbase +
                ((size_t)(cc * 4 + g) * 256 + ot * 128 + oh * 64 + lane) * 8;
            g2l16(src, &As[ring][g][oh * 64][0]);
        }
    };

    // zero Xs (borders + OOB rows stay zero forever)
    {
        short8 z = {0, 0, 0, 0, 0, 0, 0, 0};
        short8* p0 = reinterpret_cast<short8*>(&Xs[0][0][0][0]);
        for (int i = tid; i < 2080; i += 256) p0[i] = z;
    }
    __syncthreads();

    // prologue: A rings 0..3 (ps=0..3) + X chunk 0 direct-to-LDS
    stageA(0, 0, 0); stageA(0, 1, 1); stageA(0, 2, 2); stageA(0, 3, 3);
    {
        int hr = h0 + wid - 1;
        bool oob = ((unsigned)hr >= 128u);
        int hc = oob ? 0 : hr;
#pragma unroll
        for (int k = 0; k < 8; ++k) {
            int g = k >> 1, half = k & 1;
            const u16* src = xb +
                ((((size_t)(b * 32 + g)) * 128 + hc) * 128 + half * 64 + lane) * 8;
            void* dst = oob ? (void*)trash : (void*)&Xs[wid][g][1 + half * 64][0];
            g2l16(src, dst);
        }
    }
    WAITV(0);
    BARRIER();

    f32x4 acc[4][8] = {};
    short8 xr[8];
    int rr = 0, rw = 4, cs = 0, ts = 4; // read ring; write ring; next stage (chunk,tap)

    auto doPhase = [&](int t, int ring) {
        int kh = t / 3, kw = t - kh * 3;
        short8 af[4], bx8[8];
#pragma unroll
        for (int mi = 0; mi < 4; ++mi)
            af[mi] = *reinterpret_cast<const short8*>(
                &As[ring][lg][wm * 64 + mi * 16 + l15][0]);
#pragma unroll
        for (int ni = 0; ni < 8; ++ni)
            bx8[ni] = *reinterpret_cast<const short8*>(
                &Xs[wr + kh][lg][ni * 16 + l15 + kw][0]);
        __builtin_amdgcn_s_setprio(1);
#pragma unroll
        for (int mi = 0; mi < 4; ++mi)
#pragma unroll
            for (int ni = 0; ni < 8; ++ni)
                acc[mi][ni] = __builtin_amdgcn_mfma_f32_16x16x32_bf16(
                    af[mi], bx8[ni], acc[mi][ni], 0, 0, 0);
        __builtin_amdgcn_s_setprio(0);
    };

    int hr = h0 + wid - 1;
    bool hValid = ((unsigned)hr < 128u);
    int hc = hValid ? hr : 0;

    for (int c = 0; c < 7; ++c) {
#pragma unroll
        for (int t = 0; t < 9; ++t) {
            stageA(cs, ts, rw);
            if (++ts == 9) { ts = 0; ++cs; }
            if (t == 5) { // reg-stage X(c+1): 8 loads AFTER this phase's A issue
#pragma unroll
                for (int k = 0; k < 8; ++k) {
                    int g = k >> 1, half = k & 1;
                    xr[k] = *reinterpret_cast<const short8*>(xb +
                        ((((size_t)(b * 32 + (c + 1) * 4 + g)) * 128 + hc) * 128 +
                         half * 64 + lane) * 8);
                }
            }
            doPhase(t, rr);
            rr = (rr == 4) ? 0 : rr + 1;
            rw = (rw == 4) ? 0 : rw + 1;
            if (t <= 4)      { WAITV(6); }  // drain A(p+1); keep A(p+2..4)
            else if (t <= 7) { WAITV(14); } // keep X:8 + 3 A stages in flight
            else             { WAITV(6); }  // drain A(q')+X; keep A(q'+1..3)
            BARRIER();
            if (t == 8) { // write reg-staged X(c+1) into Xs
                if (hValid) {
#pragma unroll
                    for (int k = 0; k < 8; ++k) {
                        int g = k >> 1, half = k & 1;
                        *reinterpret_cast<short8*>(
                            &Xs[wid][g][1 + half * 64 + lane][0]) = xr[k];
                    }
                }
                asm volatile("s_waitcnt lgkmcnt(0)" ::: "memory");
                BARRIER();
            }
        }
    }
    // tail chunk c == 7: stages end at ps=71 (t<=4); ramp vmcnt down, never stall early
#pragma unroll
    for (int t = 0; t < 9; ++t) {
        if (t <= 4) {
            stageA(cs, ts, rw);
            if (++ts == 9) { ts = 0; ++cs; }
            rw = (rw == 4) ? 0 : rw + 1;
        }
        doPhase(t, rr);
        rr = (rr == 4) ? 0 : rr + 1;
        if (t <= 4)      { WAITV(6); }
        else if (t == 5) { WAITV(4); }
        else if (t == 6) { WAITV(2); }
        else if (t == 7) { WAITV(0); }
        if (t < 8) BARRIER();
    }

    // epilogue: C/D layout col=lane&15 (w), row=(lane>>4)*4+r (o)
    int h = h0 + wr;
#pragma unroll
    for (int mi = 0; mi < 4; ++mi) {
        int o = ot * 128 + wm * 64 + mi * 16 + lg * 4;
#pragma unroll
        for (int ni = 0; ni < 8; ++ni) {
            int w_ = ni * 16 + l15;
            float* op = out + (((size_t)(b * 256 + o) * 128 + h) * 128 + w_);
#pragma unroll
            for (int r = 0; r < 4; ++r)
                op[(size_t)r * 16384] = acc[mi][ni][r];
        }
    }
}

extern "C" void kernel_launch(void* const* d_in, const int* in_sizes, int n_in,
                              void* d_out, int out_size, void* d_ws, size_t ws_size,
                              hipStream_t stream) {
    const float* x        = (const float*)d_in[0];
    const float* w        = (const float*)d_in[1];
    const float* weight   = (const float*)d_in[2];
    const float* affine_w = (const float*)d_in[3];
    const float* affine_b = (const float*)d_in[4];
    float* out = (float*)d_out;

    float* style = (float*)d_ws;                                   // 8 KB
    u16* wgt = (u16*)((char*)d_ws + 8192);                         // 9.44 MB
    u16* xbuf = (u16*)((char*)d_ws + 8192 + 9437184);              // 64 MB

    xform_kernel<<<16384, 256, 0, stream>>>(x, xbuf);
    style_kernel<<<8, 256, 0, stream>>>(w, affine_w, affine_b, style);
    modw_kernel<<<2048, 256, 0, stream>>>(weight, style, wgt);
    conv_kernel<<<1024, 256, 0, stream>>>(xbuf, wgt, out);
}